// Round 2
// baseline (3560.424 us; speedup 1.0000x reference)
//
#include <hip/hip_runtime.h>

#define SEQ   2048
#define NM    8192        // SEQ*BATCH

typedef __attribute__((ext_vector_type(4))) float f4;
typedef _Float16 f16x8 __attribute__((ext_vector_type(8)));

__device__ __forceinline__ float frcp(float x){ return __builtin_amdgcn_rcpf(x); }
__device__ __forceinline__ float sigm(float x){ return frcp(1.f + __expf(-x)); }
__device__ __forceinline__ float tanhf_(float x){ return 1.f - 2.f*frcp(__expf(2.f*x) + 1.f); }
__device__ __forceinline__ f4 mfma16h(f16x8 a, f16x8 b, f4 c){
  return __builtin_amdgcn_mfma_f32_16x16x32_f16(a, b, c, 0, 0, 0);
}
// LDS-only barrier: scan h coherence needs lgkmcnt(0) only; global prefetch
// loads stay in flight across the barrier.
__device__ __forceinline__ void barrier_lds_only(){
  asm volatile("s_waitcnt lgkmcnt(0)\n\ts_barrier" ::: "memory");
}

// ---------------------------------------------------------------------------
// Generic tiled GEMM (256 thr): out = A[M,K] @ W[N,K]^T (+bias), epilogues.
// mode 0: plain   mode 2: LSTM-G store [dir][t][b][n'] with PERMUTED gate
// order n' = j*4 + gate (j = h-col, gate = i,f,g,o).  R15: this layout lets
// the scan's MFMA D-tile deliver each (col,batch)'s {i,f,g,o} quadruple into
// one lane's 4 accumulator regs (no LDS gate redistribution).
// ---------------------------------------------------------------------------
__global__ __launch_bounds__(256) void gemm_k(
    const float* __restrict__ A, int lda,
    const float* __restrict__ W0, const float* __restrict__ W1, int Nhalf,
    const float* __restrict__ b0a, const float* __restrict__ b0b,
    const float* __restrict__ b1a, const float* __restrict__ b1b,
    float* __restrict__ out, int M, int N, int K, int mode)
{
  __shared__ alignas(16) float As[16][68];   // [k][row]
  __shared__ alignas(16) float Ws[16][68];   // [k][col]
  const int tid = threadIdx.x;
  const int tn = tid & 15, tm = tid >> 4;
  const int n0 = blockIdx.x * 64, m0 = blockIdx.y * 64;
  const int srow = tid >> 2, sk = (tid & 3) * 4;
  float acc[4][4] = {};
  for (int k0 = 0; k0 < K; k0 += 16) {
    const int am = m0 + srow;
    #pragma unroll
    for (int q = 0; q < 4; ++q) {
      int k = k0 + sk + q;
      As[sk + q][srow] = (k < K) ? A[(size_t)am * lda + k] : 0.f;
    }
    const int wn = n0 + srow;
    const float* Wp = W0; int nn = wn;
    if (W1 != nullptr && wn >= Nhalf) { Wp = W1; nn = wn - Nhalf; }
    #pragma unroll
    for (int q = 0; q < 4; ++q) {
      int k = k0 + sk + q;
      Ws[sk + q][srow] = (wn < N && k < K) ? Wp[(size_t)nn * K + k] : 0.f;
    }
    __syncthreads();
    #pragma unroll
    for (int k = 0; k < 16; ++k) {
      f4 a = *(const f4*)&As[k][tm*4];
      f4 w = *(const f4*)&Ws[k][tn*4];
      #pragma unroll
      for (int i = 0; i < 4; ++i)
        #pragma unroll
        for (int j = 0; j < 4; ++j) acc[i][j] += a[i]*w[j];
    }
    __syncthreads();
  }
  #pragma unroll
  for (int i = 0; i < 4; ++i) {
    #pragma unroll
    for (int j = 0; j < 4; ++j) {
      int m = m0 + tm*4 + i, n = n0 + tn*4 + j;
      if (n >= N) continue;
      float bias = 0.f;
      if (n < Nhalf) { if (b0a) bias += b0a[n]; if (b0b) bias += b0b[n]; }
      else { if (b1a) bias += b1a[n - Nhalf]; if (b1b) bias += b1b[n - Nhalf]; }
      float v = acc[i][j] + bias;
      if (mode == 2) {
        int dd = n >> 8, r = n & 255, t = m >> 2, b = m & 3;
        int gate = r >> 6, jj = r & 63;
        int tq = dd ? (SEQ - 1 - t) : t;
        out[((size_t)(dd*SEQ + tq) * 4 + b) * 256 + (jj << 2) + gate] = v;
      } else {
        out[(size_t)m * N + n] = v;
      }
    }
  }
}

// W' = inprojW @ mprojW (512x23, row stride 23), b' = inprojW @ mprojB (512)
__global__ __launch_bounds__(256) void wcomb_k(
    const float* __restrict__ inprojW, const float* __restrict__ mprojW,
    const float* __restrict__ mprojB, float* __restrict__ wc,
    float* __restrict__ bvec)
{
  int idx = blockIdx.x * 256 + threadIdx.x;
  if (idx >= 512 * 24) return;
  int n = idx / 24, c = idx % 24;
  const float* wi = inprojW + (size_t)n * 128;
  float s = 0.f;
  if (c < 23) {
    for (int k = 0; k < 128; ++k) s += wi[k] * mprojW[k*23 + c];
    wc[n*23 + c] = s;
  } else {
    for (int k = 0; k < 128; ++k) s += wi[k] * mprojB[k];
    bvec[n] = s;
  }
}

// out = yc @ Wp[128,256]^T with yc computed inline: yc = (ys + xc*D)*silu(z).
__global__ __launch_bounds__(256) void moutproj_k(
    const float* __restrict__ z, const float* __restrict__ ys,
    const float* __restrict__ xc, const float* __restrict__ Dsk,
    const float* __restrict__ Wp, float* __restrict__ out)
{
  __shared__ alignas(16) float As[16][68];
  __shared__ alignas(16) float Ws[16][68];
  const int tid = threadIdx.x;
  const int tn = tid & 15, tm = tid >> 4;
  const int n0 = blockIdx.x * 64, m0 = blockIdx.y * 64;
  const int srow = tid >> 2, sk = (tid & 3) * 4;
  float acc[4][4] = {};
  for (int k0 = 0; k0 < 256; k0 += 16) {
    #pragma unroll
    for (int q = 0; q < 4; ++q) {
      int k = k0 + sk + q;
      size_t idx = (size_t)(m0 + srow) * 256 + k;
      float zz = z[idx];
      As[sk + q][srow] = (ys[idx] + xc[idx]*Dsk[k]) * zz * sigm(zz);
      Ws[sk + q][srow] = Wp[(size_t)(n0 + srow) * 256 + k];
    }
    __syncthreads();
    #pragma unroll
    for (int k = 0; k < 16; ++k) {
      f4 a = *(const f4*)&As[k][tm*4];
      f4 w = *(const f4*)&Ws[k][tn*4];
      #pragma unroll
      for (int i = 0; i < 4; ++i)
        #pragma unroll
        for (int j = 0; j < 4; ++j) acc[i][j] += a[i]*w[j];
    }
    __syncthreads();
  }
  #pragma unroll
  for (int i = 0; i < 4; ++i)
    #pragma unroll
    for (int j = 0; j < 4; ++j)
      out[(size_t)(m0 + tm*4 + i) * 128 + n0 + tn*4 + j] = acc[i][j];
}

// ---------------------------------------------------------------------------
// FUSED launch (256 thr): blocks 0-1 = LSTM scan (one dir each, 4 waves);
// blocks 2+ = one mamba pipeline stage.
// R15 SCAN: swapped-operand MFMA with gate-interleaved W rows (n' = j*4+gate);
// {i,f,g,o} land in-lane, redistribution = 4-way reg select; 1 f4 G-load/step.
// R16: lds_pad inflates static LDS to ~84 KB -> exactly ONE block per CU.
//   Scan blocks own their CU exclusively: rider blocks (stage-0/2 gemm's
//   heavy scalar ds_read streams, conv) can no longer queue on the scan CU's
//   DS pipe / VMEM queues, which sits 1:1 on the serial h-exchange chain.
//   s_setprio wins issue arbitration but not in-flight DS queueing; this does.
//   Riders drop to 4 waves/CU but have >5x slack under the ~700us scan.
// ---------------------------------------------------------------------------
__global__ __launch_bounds__(256, 1) void fused_k(
    int stage,
    const float* __restrict__ G,    // [2][SEQ][4][256] (permuted n' = j*4+gate)
    const float* __restrict__ Whh,  // [2][256][64] (layer base)
    float* __restrict__ lout,       // [SEQ][4][128]
    const float* __restrict__ rA, int lda,
    const float* __restrict__ rW, const float* __restrict__ rbias,
    float* __restrict__ rout, int ldo, int N, int K,
    const float* __restrict__ dtW, const float* __restrict__ dtB,
    float* __restrict__ dtout,
    const float* __restrict__ mdbc, const float* __restrict__ mdtb,
    const float* __restrict__ mxc, const float* __restrict__ mAlog,
    float* __restrict__ mys)
{
  __shared__ alignas(16) _Float16 hb2[2][4][80]; // scan: [buf][batch][hcol]
  __shared__ float As[64][17];            // gemm rider
  __shared__ float Ws[64][17];            // gemm rider
  __shared__ float dtl[64][8];            // stage-2 dt fusion
  __shared__ float lds_pad[18432];        // 72KB: force 1 block/CU (R16)

  const int tid = threadIdx.x;
  if (stage == -1) ((volatile float*)lds_pad)[tid] = 0.f;  // never true: keeps pad

  if (blockIdx.x < 2) {
    // ---------------- LSTM scan ----------------
    __builtin_amdgcn_s_setprio(1);
    const int dir = blockIdx.x;
    const int w = tid >> 6, lane = tid & 63;   // w in 0..3
    const int q = lane >> 4, c = lane & 15;
    const int bb = c & 3, sel = c >> 2;        // batch, tile-select
    const int mtile = 4*sel + w;               // owned tile
    const int jcol = mtile*4 + q;              // owned h-col (0..63)

    for (int i = tid; i < 2*4*80; i += 256) ((_Float16*)hb2)[i] = (_Float16)0.f;

    const float* Gd = G + (size_t)dir * SEQ * 1024;
    const float* Wd = Whh + dir * 256 * 64;

    // A fragments: wave w owns tiles {4s+w}; tile m row (lane&15)=c maps to
    // n' = m*16 + c -> orig Whh row (c&3)*64 + m*4 + (c>>2).
    f16x8 Wf[4][2];
    #pragma unroll
    for (int s2 = 0; s2 < 4; ++s2) {
      const int m = 4*s2 + w;
      const int orow = (c & 3)*64 + m*4 + (c >> 2);
      #pragma unroll
      for (int kt = 0; kt < 2; ++kt) {
        const float* src = Wd + orow*64 + kt*32 + q*8;
        #pragma unroll
        for (int e = 0; e < 8; ++e) Wf[s2][kt][e] = (_Float16)src[e];
      }
    }

    float cc = 0.f;      // cell state: lane owns (col jcol, batch bb)

    auto loadG = [&](int t) -> f4 {
      return *(const f4*)(Gd + (((size_t)t*4 + bb) << 8) + mtile*16 + q*4);
    };
    f4 gp0 = loadG(0), gp1 = loadG(1), gp2 = loadG(2), gp3 = loadG(3);
    __syncthreads();

    auto step = [&](int t, f4 gv) {
      const int p0 = t & 1, p1 = p0 ^ 1;
      const f16x8 h0 = *(const f16x8*)&hb2[p0][bb][q*8];       // k = q*8+e
      const f16x8 h1 = *(const f16x8*)&hb2[p0][bb][32 + q*8];  // k = 32+q*8+e
      // gv is correct C-seed only for tile sel (the lane's used tile);
      // other tiles' D at this lane is unused.
      f4 a0 = mfma16h(Wf[0][0], h0, gv); a0 = mfma16h(Wf[0][1], h1, a0);
      f4 a1 = mfma16h(Wf[1][0], h0, gv); a1 = mfma16h(Wf[1][1], h1, a1);
      f4 a2 = mfma16h(Wf[2][0], h0, gv); a2 = mfma16h(Wf[2][1], h1, a2);
      f4 a3 = mfma16h(Wf[3][0], h0, gv); a3 = mfma16h(Wf[3][1], h1, a3);
      // 4-way register select: g4 = a[sel]  (regs = gates i,f,g,o of jcol,bb)
      const bool sb0 = (sel & 1) != 0, sb1 = (sel & 2) != 0;
      f4 g4;
      #pragma unroll
      for (int r = 0; r < 4; ++r) {
        float x01 = sb0 ? a1[r] : a0[r];
        float x23 = sb0 ? a3[r] : a2[r];
        g4[r] = sb1 ? x23 : x01;
      }
      cc = sigm(g4[1])*cc + sigm(g4[0])*tanhf_(g4[2]);
      const float hh = sigm(g4[3])*tanhf_(cc);
      hb2[p1][bb][jcol] = (_Float16)hh;
      const int to = dir ? (SEQ-1 - t) : t;
      lout[((size_t)to*4 + bb)*128 + dir*64 + jcol] = hh;
      barrier_lds_only();           // single barrier: publish h
    };

    for (int t0 = 0; t0 < SEQ; t0 += 4) {
      step(t0+0, gp0); if (t0+4 < SEQ) gp0 = loadG(t0+4);
      step(t0+1, gp1); if (t0+5 < SEQ) gp1 = loadG(t0+5);
      step(t0+2, gp2); if (t0+6 < SEQ) gp2 = loadG(t0+6);
      step(t0+3, gp3); if (t0+7 < SEQ) gp3 = loadG(t0+7);
    }
    return;
  }

  // ---------------- mamba riders ----------------
  int rb = blockIdx.x - 2;

  if (stage == 1) {       // conv4 + silu: xi [NM,256] -> xc [NM,256]
    int idx = rb*256 + tid;          // < NM*256
    int d = idx & 255, m2 = idx >> 8;
    int t = m2 >> 2, b = m2 & 3;
    float s = rbias[d];
    #pragma unroll
    for (int k = 0; k < 4; ++k) {
      int tt = t - 3 + k;
      if (tt >= 0) s += rA[(size_t)((tt*4 + b) << 8) + d] * rW[d*4 + k];
    }
    rout[idx] = s * sigm(s);
    return;
  }

  if (stage == 3) {       // selective scan, wave per (b,d)
    const int wid = rb*4 + (tid >> 6);
    const int lane = tid & 63;
    const int b = wid >> 8, d = wid & 255;
    const float Av = -__expf(mAlog[d*64 + lane]);
    const float* pB  = mdbc + (size_t)b*136 + 8 + lane;
    const float* pC  = mdbc + (size_t)b*136 + 72 + lane;
    const float* pdt = mdtb + (size_t)b*256 + d;
    const float* px  = mxc  + (size_t)b*256 + d;
    float* py = mys + (size_t)b*256 + d;
    float h = 0.f;
    float Bv = pB[0], Cv = pC[0], dtv = pdt[0], xv = px[0];
    #pragma unroll 2
    for (int t = 0; t < SEQ; ++t) {
      float Bn = 0.f, Cn = 0.f, dtn = 0.f, xn = 0.f;
      if (t + 1 < SEQ) {
        size_t od = (size_t)(t+1) * 544;
        size_t ox = (size_t)(t+1) * 1024;
        Bn = pB[od]; Cn = pC[od]; dtn = pdt[ox]; xn = px[ox];
      }
      float a = __expf(dtv * Av);
      h = a*h + (dtv*xv)*Bv;
      float p = h * Cv;
      #pragma unroll
      for (int mm = 1; mm < 64; mm <<= 1) p += __shfl_xor(p, mm, 64);
      if (lane == 0) py[(size_t)t * 1024] = p;
      Bv = Bn; Cv = Cn; dtv = dtn; xv = xn;
    }
    return;
  }

  // stage 0 / 2: 64x64-tile gemm rider (256 threads).
  const float* gW = rW; const float* gB = rbias; float* gO = rout;
  if (stage == 0 && rb >= 512) { rb -= 512; gW = dtW; gB = dtB; gO = dtout; }
  const int ntiles = (N + 63) >> 6;
  const int nt = rb % ntiles, mt = rb / ntiles;
  const int n0 = nt * 64, m0 = mt * 64;
  const int tn = tid & 15, tm = tid >> 4;
  const int srow = tid >> 2, sk = (tid & 3) * 4;
  float acc[4][4] = {};
  for (int k0 = 0; k0 < K; k0 += 16) {
    #pragma unroll
    for (int qq = 0; qq < 4; ++qq) {
      int k = k0 + sk + qq;
      As[srow][sk + qq] = (k < K) ? rA[(size_t)(m0 + srow) * lda + k] : 0.f;
      Ws[srow][sk + qq] = (n0 + srow < N && k < K) ? gW[(size_t)(n0 + srow) * K + k] : 0.f;
    }
    __syncthreads();
    #pragma unroll
    for (int k = 0; k < 16; ++k) {
      float a[4], w[4];
      #pragma unroll
      for (int i = 0; i < 4; ++i) a[i] = As[tm*4+i][k];
      #pragma unroll
      for (int j = 0; j < 4; ++j) w[j] = Ws[tn*4+j][k];
      #pragma unroll
      for (int i = 0; i < 4; ++i)
        #pragma unroll
        for (int j = 0; j < 4; ++j) acc[i][j] += a[i]*w[j];
    }
    __syncthreads();
  }
  #pragma unroll
  for (int i = 0; i < 4; ++i) {
    #pragma unroll
    for (int j = 0; j < 4; ++j) {
      int m2 = m0 + tm*4 + i, n = n0 + tn*4 + j;
      if (n >= N) continue;
      float v = acc[i][j] + (gB ? gB[n] : 0.f);
      gO[(size_t)m2 * ldo + n] = v;
      if (stage == 2 && nt == 0 && n < 8) dtl[tm*4+i][n] = v;
    }
  }
  if (stage == 2 && nt == 0) {
    // dt = softplus(dbc[:, :8] @ dtW^T + dtB) for this block's 64 rows
    __syncthreads();
    for (int idx = tid; idx < 64*256; idx += 256) {
      int ml = idx >> 8, d = idx & 255;
      float s = dtB[d];
      #pragma unroll
      for (int r = 0; r < 8; ++r) s += dtl[ml][r] * dtW[d*8 + r];
      s = (s > 15.f) ? s : __logf(1.f + __expf(s));
      dtout[(size_t)(m0 + ml)*256 + d] = s;
    }
  }
}

// final LayerNorm(concat) -> gate -> mix.  One wave per (t,b).
__global__ __launch_bounds__(256) void combine_k(
    const float* __restrict__ lstm, const float* __restrict__ mam,
    const float* __restrict__ lnw, const float* __restrict__ lnb,
    const float* __restrict__ gW, const float* __restrict__ gb,
    float* __restrict__ out)
{
  const int pair = blockIdx.x * 4 + (threadIdx.x >> 6);
  const int lane = threadIdx.x & 63;
  const float2 lv = *(const float2*)(lstm + (size_t)pair*128 + lane*2);
  const float2 mv = *(const float2*)(mam  + (size_t)pair*128 + lane*2);
  float s  = lv.x + lv.y + mv.x + mv.y;
  float sq = lv.x*lv.x + lv.y*lv.y + mv.x*mv.x + mv.y*mv.y;
  #pragma unroll
  for (int mm = 1; mm < 64; mm <<= 1) { s += __shfl_xor(s, mm, 64); sq += __shfl_xor(sq, mm, 64); }
  const float mean = s * (1.f/256.f);
  const float var  = sq * (1.f/256.f) - mean*mean;
  const float inv  = rsqrtf(var + 1e-5f);
  const int c0 = lane*2, c2 = 128 + lane*2;
  float n0 = (lv.x-mean)*inv*lnw[c0]   + lnb[c0];
  float n1 = (lv.y-mean)*inv*lnw[c0+1] + lnb[c0+1];
  float n2 = (mv.x-mean)*inv*lnw[c2]   + lnb[c2];
  float n3 = (mv.y-mean)*inv*lnw[c2+1] + lnb[c2+1];
  float dot = n0*gW[c0] + n1*gW[c0+1] + n2*gW[c2] + n3*gW[c2+1];
  #pragma unroll
  for (int mm = 1; mm < 64; mm <<= 1) dot += __shfl_xor(dot, mm, 64);
  const float gate = sigm(dot + gb[0]);
  float2 o;
  o.x = gate*lv.x + (1.f-gate)*mv.x;
  o.y = gate*lv.y + (1.f-gate)*mv.y;
  *(float2*)(out + (size_t)pair*128 + lane*2) = o;
}

extern "C" void kernel_launch(void* const* d_in, const int* in_sizes, int n_in,
                              void* d_out, int out_size, void* d_ws, size_t ws_size,
                              hipStream_t stream)
{
  const float* x       = (const float*)d_in[0];
  const float* Wih0    = (const float*)d_in[1];
  const float* WihR    = (const float*)d_in[2];
  const float* Whh     = (const float*)d_in[3];
  const float* bih     = (const float*)d_in[4];
  const float* bhh     = (const float*)d_in[5];
  const float* mprojW  = (const float*)d_in[6];
  const float* mprojB  = (const float*)d_in[7];
  const float* inprojW = (const float*)d_in[8];
  const float* convw   = (const float*)d_in[9];
  const float* convb   = (const float*)d_in[10];
  const float* xprojW  = (const float*)d_in[11];
  const float* dtW     = (const float*)d_in[12];
  const float* dtB     = (const float*)d_in[13];
  const float* Alog    = (const float*)d_in[14];
  const float* Dskip   = (const float*)d_in[15];
  const float* outprojW= (const float*)d_in[16];
  const float* lnw     = (const float*)d_in[17];
  const float* lnb     = (const float*)d_in[18];
  const float* gWt     = (const float*)d_in[19];
  const float* gb      = (const float*)d_in[20];

  float* WS = (float*)d_ws;
  const size_t M1 = 1048576;
  float* mamba_out = WS;                    // [NM,128]
  float* P     = WS + M1;
  float* G     = P;                         // [2][SEQ][4][256] = 4M1 (lstm)
  float* lstmA = P + 4*M1;                  // [NM,128]
  float* lstmB = P + 5*M1;                  // [NM,128]
  float* xi    = P + 6*M1;                  // [NM,256] (F0 out, F1 in)
  float* dtb   = P + 6*M1;                  // alias: [NM,256] (F2 out, F3 in)
  float* xc    = P + 8*M1;                  // [NM,256] (F1 out; F2, tail in)
  float* dbc   = P + 10*M1;                 // [NM,136] (F2 out, F3 in)
  float* wc    = P + 10*M1 + (size_t)NM*136;// [512][23]
  float* bvec  = wc + 512*23;               // [512]
  float* ysb   = P + 11*M1 + M1/4;          // [NM,256] (F3 out, tail in)
  const bool zOK = ws_size >= 65ull*1048576;
  float* zbuf  = zOK ? (P + 13*M1 + M1/4)   // [NM,256], written in l=0 launch
                     : (P + 6*M1);          // fallback: alias, tail z-gemm
  float* outp  = (float*)d_out;

  dim3 blk(256);

  // pre: fold mproj into in_proj
  wcomb_k<<<48, blk, 0, stream>>>(inprojW, mprojW, mprojB, wc, bvec);

  // ---- LSTM layers with mamba stages riding the scan launches ----
  const float* lin = x;
  float* louts[4] = {lstmA, lstmB, lstmA, lstmB};
  for (int l = 0; l < 4; ++l) {
    const float* w0; const float* w1; int K;
    if (l == 0) { w0 = Wih0; w1 = Wih0 + 256*23; K = 23; }
    else {
      w0 = WihR + (size_t)((l-1)*2 + 0)*256*128;
      w1 = WihR + (size_t)((l-1)*2 + 1)*256*128;
      K = 128;
    }
    gemm_k<<<dim3(8,128), blk, 0, stream>>>(lin, K, w0, w1, 256,
        bih + (l*2+0)*256, bhh + (l*2+0)*256,
        bih + (l*2+1)*256, bhh + (l*2+1)*256,
        G, NM, 512, K, 2);
    const float* Wl = Whh + (size_t)l*2*256*64;
    if (l == 0) {        // rider: xi = x @ W'[0:256]^T + b' (+ optional z)
      fused_k<<<2 + (zOK ? 1024 : 512), blk, 0, stream>>>(0, G, Wl, louts[l],
          x, 23, wc, bvec, xi, 256, 256, 23,
          zOK ? (wc + 256*23) : nullptr, zOK ? (bvec + 256) : nullptr,
          zOK ? zbuf : nullptr, nullptr, nullptr, nullptr, nullptr, nullptr);
    } else if (l == 1) { // rider: conv+silu (NM*256 / 256 blocks)
      fused_k<<<2 + 8192, blk, 0, stream>>>(1, G, Wl, louts[l],
          xi, 0, convw, convb, xc, 0, 0, 0,
          nullptr, nullptr, nullptr, nullptr, nullptr, nullptr, nullptr, nullptr);
    } else if (l == 2) { // rider: xproj (3 x 128 tiles) + fused dt
      fused_k<<<2 + 384, blk, 0, stream>>>(2, G, Wl, louts[l],
          xc, 256, xprojW, nullptr, dbc, 136, 136, 256,
          dtW, dtB, dtb, nullptr, nullptr, nullptr, nullptr, nullptr);
    } else {             // rider: mamba selective scan (256 blocks x 4 waves)
      fused_k<<<2 + 256, blk, 0, stream>>>(3, G, Wl, louts[l],
          nullptr, 0, nullptr, nullptr, nullptr, 0, 0, 0,
          nullptr, nullptr, nullptr, dbc, dtb, xc, Alog, ysb);
    }
    lin = louts[l];
  }

  // ---- tail: [z-gemm if not ridden], fused ycomb+out_proj, gate+mix ----
  if (!zOK) {
    gemm_k<<<dim3(4,128), blk, 0, stream>>>(x, 23, wc + 256*23, nullptr, 256,
        bvec + 256, nullptr, nullptr, nullptr, zbuf, NM, 256, 23, 0);
  }
  moutproj_k<<<dim3(2,128), blk, 0, stream>>>(zbuf, ysb, xc, Dskip,
      outprojW, mamba_out);
  combine_k<<<2048, blk, 0, stream>>>(lstmB, mamba_out, lnw, lnb, gWt, gb, outp);
}

// Round 3
// 2987.466 us; speedup vs baseline: 1.1918x; 1.1918x over previous
//
#include <hip/hip_runtime.h>

#define SEQ   2048
#define NM    8192        // SEQ*BATCH

typedef __attribute__((ext_vector_type(4))) float f4;
typedef _Float16 f16x8 __attribute__((ext_vector_type(8)));

__device__ __forceinline__ float frcp(float x){ return __builtin_amdgcn_rcpf(x); }
__device__ __forceinline__ float sigm(float x){ return frcp(1.f + __expf(-x)); }
__device__ __forceinline__ float tanhf_(float x){ return 1.f - 2.f*frcp(__expf(2.f*x) + 1.f); }
__device__ __forceinline__ f4 mfma16h(f16x8 a, f16x8 b, f4 c){
  return __builtin_amdgcn_mfma_f32_16x16x32_f16(a, b, c, 0, 0, 0);
}
// LDS-only barrier: scan h coherence needs lgkmcnt(0) only; global prefetch
// loads stay in flight across the barrier.
__device__ __forceinline__ void barrier_lds_only(){
  asm volatile("s_waitcnt lgkmcnt(0)\n\ts_barrier" ::: "memory");
}

// ---------------------------------------------------------------------------
// Generic tiled GEMM (256 thr): out = A[M,K] @ W[N,K]^T (+bias), epilogues.
// mode 0: plain   mode 2: LSTM-G store [dir][t][b][n'] with PERMUTED gate
// order n' = j*4 + gate (j = h-col, gate = i,f,g,o).  R15: this layout lets
// the scan's MFMA D-tile deliver each (col,batch)'s {i,f,g,o} quadruple into
// one lane's 4 accumulator regs (no LDS gate redistribution).
// ---------------------------------------------------------------------------
__global__ __launch_bounds__(256) void gemm_k(
    const float* __restrict__ A, int lda,
    const float* __restrict__ W0, const float* __restrict__ W1, int Nhalf,
    const float* __restrict__ b0a, const float* __restrict__ b0b,
    const float* __restrict__ b1a, const float* __restrict__ b1b,
    float* __restrict__ out, int M, int N, int K, int mode)
{
  __shared__ alignas(16) float As[16][68];   // [k][row]
  __shared__ alignas(16) float Ws[16][68];   // [k][col]
  const int tid = threadIdx.x;
  const int tn = tid & 15, tm = tid >> 4;
  const int n0 = blockIdx.x * 64, m0 = blockIdx.y * 64;
  const int srow = tid >> 2, sk = (tid & 3) * 4;
  float acc[4][4] = {};
  for (int k0 = 0; k0 < K; k0 += 16) {
    const int am = m0 + srow;
    #pragma unroll
    for (int q = 0; q < 4; ++q) {
      int k = k0 + sk + q;
      As[sk + q][srow] = (k < K) ? A[(size_t)am * lda + k] : 0.f;
    }
    const int wn = n0 + srow;
    const float* Wp = W0; int nn = wn;
    if (W1 != nullptr && wn >= Nhalf) { Wp = W1; nn = wn - Nhalf; }
    #pragma unroll
    for (int q = 0; q < 4; ++q) {
      int k = k0 + sk + q;
      Ws[sk + q][srow] = (wn < N && k < K) ? Wp[(size_t)nn * K + k] : 0.f;
    }
    __syncthreads();
    #pragma unroll
    for (int k = 0; k < 16; ++k) {
      f4 a = *(const f4*)&As[k][tm*4];
      f4 w = *(const f4*)&Ws[k][tn*4];
      #pragma unroll
      for (int i = 0; i < 4; ++i)
        #pragma unroll
        for (int j = 0; j < 4; ++j) acc[i][j] += a[i]*w[j];
    }
    __syncthreads();
  }
  #pragma unroll
  for (int i = 0; i < 4; ++i) {
    #pragma unroll
    for (int j = 0; j < 4; ++j) {
      int m = m0 + tm*4 + i, n = n0 + tn*4 + j;
      if (n >= N) continue;
      float bias = 0.f;
      if (n < Nhalf) { if (b0a) bias += b0a[n]; if (b0b) bias += b0b[n]; }
      else { if (b1a) bias += b1a[n - Nhalf]; if (b1b) bias += b1b[n - Nhalf]; }
      float v = acc[i][j] + bias;
      if (mode == 2) {
        int dd = n >> 8, r = n & 255, t = m >> 2, b = m & 3;
        int gate = r >> 6, jj = r & 63;
        int tq = dd ? (SEQ - 1 - t) : t;
        out[((size_t)(dd*SEQ + tq) * 4 + b) * 256 + (jj << 2) + gate] = v;
      } else {
        out[(size_t)m * N + n] = v;
      }
    }
  }
}

// W' = inprojW @ mprojW (512x23, row stride 23), b' = inprojW @ mprojB (512)
__global__ __launch_bounds__(256) void wcomb_k(
    const float* __restrict__ inprojW, const float* __restrict__ mprojW,
    const float* __restrict__ mprojB, float* __restrict__ wc,
    float* __restrict__ bvec)
{
  int idx = blockIdx.x * 256 + threadIdx.x;
  if (idx >= 512 * 24) return;
  int n = idx / 24, c = idx % 24;
  const float* wi = inprojW + (size_t)n * 128;
  float s = 0.f;
  if (c < 23) {
    for (int k = 0; k < 128; ++k) s += wi[k] * mprojW[k*23 + c];
    wc[n*23 + c] = s;
  } else {
    for (int k = 0; k < 128; ++k) s += wi[k] * mprojB[k];
    bvec[n] = s;
  }
}

// out = yc @ Wp[128,256]^T with yc computed inline: yc = (ys + xc*D)*silu(z).
__global__ __launch_bounds__(256) void moutproj_k(
    const float* __restrict__ z, const float* __restrict__ ys,
    const float* __restrict__ xc, const float* __restrict__ Dsk,
    const float* __restrict__ Wp, float* __restrict__ out)
{
  __shared__ alignas(16) float As[16][68];
  __shared__ alignas(16) float Ws[16][68];
  const int tid = threadIdx.x;
  const int tn = tid & 15, tm = tid >> 4;
  const int n0 = blockIdx.x * 64, m0 = blockIdx.y * 64;
  const int srow = tid >> 2, sk = (tid & 3) * 4;
  float acc[4][4] = {};
  for (int k0 = 0; k0 < 256; k0 += 16) {
    #pragma unroll
    for (int q = 0; q < 4; ++q) {
      int k = k0 + sk + q;
      size_t idx = (size_t)(m0 + srow) * 256 + k;
      float zz = z[idx];
      As[sk + q][srow] = (ys[idx] + xc[idx]*Dsk[k]) * zz * sigm(zz);
      Ws[sk + q][srow] = Wp[(size_t)(n0 + srow) * 256 + k];
    }
    __syncthreads();
    #pragma unroll
    for (int k = 0; k < 16; ++k) {
      f4 a = *(const f4*)&As[k][tm*4];
      f4 w = *(const f4*)&Ws[k][tn*4];
      #pragma unroll
      for (int i = 0; i < 4; ++i)
        #pragma unroll
        for (int j = 0; j < 4; ++j) acc[i][j] += a[i]*w[j];
    }
    __syncthreads();
  }
  #pragma unroll
  for (int i = 0; i < 4; ++i)
    #pragma unroll
    for (int j = 0; j < 4; ++j)
      out[(size_t)(m0 + tm*4 + i) * 128 + n0 + tn*4 + j] = acc[i][j];
}

// ---------------------------------------------------------------------------
// FUSED launch (256 thr): blocks 0-1 = LSTM scan (one dir each, 4 waves);
// blocks 2+ = one mamba pipeline stage.
// R15 SCAN: swapped-operand MFMA with gate-interleaved W rows (n' = j*4+gate);
// {i,f,g,o} land in-lane, redistribution = 4-way reg select; 1 f4 G-load/step.
// R16 (REVERTED): 1-block/CU LDS pad slowed the scan 1.5x — codegen
//   perturbation (VGPR 68->132); rider contention theory unproven.
// R17: 8-deep G prefetch ring (was 4).  vmcnt is an ordered counter shared by
//   loads AND the per-step lout stores; with a 4-deep ring the compiler's
//   wait before each gv use sits near the store horizon, putting L2
//   store-ack latency on the serial chain.  At 8-deep the exact-count wait
//   (~vmcnt(15)) never drains a recent store, and each load has ~8 steps of
//   slack.  Math unchanged (same loads, same order of use).
// ---------------------------------------------------------------------------
__global__ __launch_bounds__(256, 1) void fused_k(
    int stage,
    const float* __restrict__ G,    // [2][SEQ][4][256] (permuted n' = j*4+gate)
    const float* __restrict__ Whh,  // [2][256][64] (layer base)
    float* __restrict__ lout,       // [SEQ][4][128]
    const float* __restrict__ rA, int lda,
    const float* __restrict__ rW, const float* __restrict__ rbias,
    float* __restrict__ rout, int ldo, int N, int K,
    const float* __restrict__ dtW, const float* __restrict__ dtB,
    float* __restrict__ dtout,
    const float* __restrict__ mdbc, const float* __restrict__ mdtb,
    const float* __restrict__ mxc, const float* __restrict__ mAlog,
    float* __restrict__ mys)
{
  __shared__ alignas(16) _Float16 hb2[2][4][80]; // scan: [buf][batch][hcol]
  __shared__ float As[64][17];            // gemm rider
  __shared__ float Ws[64][17];            // gemm rider
  __shared__ float dtl[64][8];            // stage-2 dt fusion

  const int tid = threadIdx.x;

  if (blockIdx.x < 2) {
    // ---------------- LSTM scan ----------------
    __builtin_amdgcn_s_setprio(1);
    const int dir = blockIdx.x;
    const int w = tid >> 6, lane = tid & 63;   // w in 0..3
    const int q = lane >> 4, c = lane & 15;
    const int bb = c & 3, sel = c >> 2;        // batch, tile-select
    const int mtile = 4*sel + w;               // owned tile
    const int jcol = mtile*4 + q;              // owned h-col (0..63)

    for (int i = tid; i < 2*4*80; i += 256) ((_Float16*)hb2)[i] = (_Float16)0.f;

    const float* Gd = G + (size_t)dir * SEQ * 1024;
    const float* Wd = Whh + dir * 256 * 64;

    // A fragments: wave w owns tiles {4s+w}; tile m row (lane&15)=c maps to
    // n' = m*16 + c -> orig Whh row (c&3)*64 + m*4 + (c>>2).
    f16x8 Wf[4][2];
    #pragma unroll
    for (int s2 = 0; s2 < 4; ++s2) {
      const int m = 4*s2 + w;
      const int orow = (c & 3)*64 + m*4 + (c >> 2);
      #pragma unroll
      for (int kt = 0; kt < 2; ++kt) {
        const float* src = Wd + orow*64 + kt*32 + q*8;
        #pragma unroll
        for (int e = 0; e < 8; ++e) Wf[s2][kt][e] = (_Float16)src[e];
      }
    }

    float cc = 0.f;      // cell state: lane owns (col jcol, batch bb)

    auto loadG = [&](int t) -> f4 {
      return *(const f4*)(Gd + (((size_t)t*4 + bb) << 8) + mtile*16 + q*4);
    };
    f4 gp[8];
    #pragma unroll
    for (int i = 0; i < 8; ++i) gp[i] = loadG(i);
    __syncthreads();

    auto step = [&](int t, f4 gv) {
      const int p0 = t & 1, p1 = p0 ^ 1;
      const f16x8 h0 = *(const f16x8*)&hb2[p0][bb][q*8];       // k = q*8+e
      const f16x8 h1 = *(const f16x8*)&hb2[p0][bb][32 + q*8];  // k = 32+q*8+e
      // gv is correct C-seed only for tile sel (the lane's used tile);
      // other tiles' D at this lane is unused.
      f4 a0 = mfma16h(Wf[0][0], h0, gv); a0 = mfma16h(Wf[0][1], h1, a0);
      f4 a1 = mfma16h(Wf[1][0], h0, gv); a1 = mfma16h(Wf[1][1], h1, a1);
      f4 a2 = mfma16h(Wf[2][0], h0, gv); a2 = mfma16h(Wf[2][1], h1, a2);
      f4 a3 = mfma16h(Wf[3][0], h0, gv); a3 = mfma16h(Wf[3][1], h1, a3);
      // 4-way register select: g4 = a[sel]  (regs = gates i,f,g,o of jcol,bb)
      const bool sb0 = (sel & 1) != 0, sb1 = (sel & 2) != 0;
      f4 g4;
      #pragma unroll
      for (int r = 0; r < 4; ++r) {
        float x01 = sb0 ? a1[r] : a0[r];
        float x23 = sb0 ? a3[r] : a2[r];
        g4[r] = sb1 ? x23 : x01;
      }
      cc = sigm(g4[1])*cc + sigm(g4[0])*tanhf_(g4[2]);
      const float hh = sigm(g4[3])*tanhf_(cc);
      hb2[p1][bb][jcol] = (_Float16)hh;
      const int to = dir ? (SEQ-1 - t) : t;
      lout[((size_t)to*4 + bb)*128 + dir*64 + jcol] = hh;
      barrier_lds_only();           // single barrier: publish h
    };

    for (int t0 = 0; t0 < SEQ; t0 += 8) {
      #pragma unroll
      for (int i = 0; i < 8; ++i) {
        step(t0 + i, gp[i]);
        if (t0 + 8 + i < SEQ) gp[i] = loadG(t0 + 8 + i);
      }
    }
    return;
  }

  // ---------------- mamba riders ----------------
  int rb = blockIdx.x - 2;

  if (stage == 1) {       // conv4 + silu: xi [NM,256] -> xc [NM,256]
    int idx = rb*256 + tid;          // < NM*256
    int d = idx & 255, m2 = idx >> 8;
    int t = m2 >> 2, b = m2 & 3;
    float s = rbias[d];
    #pragma unroll
    for (int k = 0; k < 4; ++k) {
      int tt = t - 3 + k;
      if (tt >= 0) s += rA[(size_t)((tt*4 + b) << 8) + d] * rW[d*4 + k];
    }
    rout[idx] = s * sigm(s);
    return;
  }

  if (stage == 3) {       // selective scan, wave per (b,d)
    const int wid = rb*4 + (tid >> 6);
    const int lane = tid & 63;
    const int b = wid >> 8, d = wid & 255;
    const float Av = -__expf(mAlog[d*64 + lane]);
    const float* pB  = mdbc + (size_t)b*136 + 8 + lane;
    const float* pC  = mdbc + (size_t)b*136 + 72 + lane;
    const float* pdt = mdtb + (size_t)b*256 + d;
    const float* px  = mxc  + (size_t)b*256 + d;
    float* py = mys + (size_t)b*256 + d;
    float h = 0.f;
    float Bv = pB[0], Cv = pC[0], dtv = pdt[0], xv = px[0];
    #pragma unroll 2
    for (int t = 0; t < SEQ; ++t) {
      float Bn = 0.f, Cn = 0.f, dtn = 0.f, xn = 0.f;
      if (t + 1 < SEQ) {
        size_t od = (size_t)(t+1) * 544;
        size_t ox = (size_t)(t+1) * 1024;
        Bn = pB[od]; Cn = pC[od]; dtn = pdt[ox]; xn = px[ox];
      }
      float a = __expf(dtv * Av);
      h = a*h + (dtv*xv)*Bv;
      float p = h * Cv;
      #pragma unroll
      for (int mm = 1; mm < 64; mm <<= 1) p += __shfl_xor(p, mm, 64);
      if (lane == 0) py[(size_t)t * 1024] = p;
      Bv = Bn; Cv = Cn; dtv = dtn; xv = xn;
    }
    return;
  }

  // stage 0 / 2: 64x64-tile gemm rider (256 threads).
  const float* gW = rW; const float* gB = rbias; float* gO = rout;
  if (stage == 0 && rb >= 512) { rb -= 512; gW = dtW; gB = dtB; gO = dtout; }
  const int ntiles = (N + 63) >> 6;
  const int nt = rb % ntiles, mt = rb / ntiles;
  const int n0 = nt * 64, m0 = mt * 64;
  const int tn = tid & 15, tm = tid >> 4;
  const int srow = tid >> 2, sk = (tid & 3) * 4;
  float acc[4][4] = {};
  for (int k0 = 0; k0 < K; k0 += 16) {
    #pragma unroll
    for (int qq = 0; qq < 4; ++qq) {
      int k = k0 + sk + qq;
      As[srow][sk + qq] = (k < K) ? rA[(size_t)(m0 + srow) * lda + k] : 0.f;
      Ws[srow][sk + qq] = (n0 + srow < N && k < K) ? gW[(size_t)(n0 + srow) * K + k] : 0.f;
    }
    __syncthreads();
    #pragma unroll
    for (int k = 0; k < 16; ++k) {
      float a[4], w[4];
      #pragma unroll
      for (int i = 0; i < 4; ++i) a[i] = As[tm*4+i][k];
      #pragma unroll
      for (int j = 0; j < 4; ++j) w[j] = Ws[tn*4+j][k];
      #pragma unroll
      for (int i = 0; i < 4; ++i)
        #pragma unroll
        for (int j = 0; j < 4; ++j) acc[i][j] += a[i]*w[j];
    }
    __syncthreads();
  }
  #pragma unroll
  for (int i = 0; i < 4; ++i) {
    #pragma unroll
    for (int j = 0; j < 4; ++j) {
      int m2 = m0 + tm*4 + i, n = n0 + tn*4 + j;
      if (n >= N) continue;
      float v = acc[i][j] + (gB ? gB[n] : 0.f);
      gO[(size_t)m2 * ldo + n] = v;
      if (stage == 2 && nt == 0 && n < 8) dtl[tm*4+i][n] = v;
    }
  }
  if (stage == 2 && nt == 0) {
    // dt = softplus(dbc[:, :8] @ dtW^T + dtB) for this block's 64 rows
    __syncthreads();
    for (int idx = tid; idx < 64*256; idx += 256) {
      int ml = idx >> 8, d = idx & 255;
      float s = dtB[d];
      #pragma unroll
      for (int r = 0; r < 8; ++r) s += dtl[ml][r] * dtW[d*8 + r];
      s = (s > 15.f) ? s : __logf(1.f + __expf(s));
      dtout[(size_t)(m0 + ml)*256 + d] = s;
    }
  }
}

// final LayerNorm(concat) -> gate -> mix.  One wave per (t,b).
__global__ __launch_bounds__(256) void combine_k(
    const float* __restrict__ lstm, const float* __restrict__ mam,
    const float* __restrict__ lnw, const float* __restrict__ lnb,
    const float* __restrict__ gW, const float* __restrict__ gb,
    float* __restrict__ out)
{
  const int pair = blockIdx.x * 4 + (threadIdx.x >> 6);
  const int lane = threadIdx.x & 63;
  const float2 lv = *(const float2*)(lstm + (size_t)pair*128 + lane*2);
  const float2 mv = *(const float2*)(mam  + (size_t)pair*128 + lane*2);
  float s  = lv.x + lv.y + mv.x + mv.y;
  float sq = lv.x*lv.x + lv.y*lv.y + mv.x*mv.x + mv.y*mv.y;
  #pragma unroll
  for (int mm = 1; mm < 64; mm <<= 1) { s += __shfl_xor(s, mm, 64); sq += __shfl_xor(sq, mm, 64); }
  const float mean = s * (1.f/256.f);
  const float var  = sq * (1.f/256.f) - mean*mean;
  const float inv  = rsqrtf(var + 1e-5f);
  const int c0 = lane*2, c2 = 128 + lane*2;
  float n0 = (lv.x-mean)*inv*lnw[c0]   + lnb[c0];
  float n1 = (lv.y-mean)*inv*lnw[c0+1] + lnb[c0+1];
  float n2 = (mv.x-mean)*inv*lnw[c2]   + lnb[c2];
  float n3 = (mv.y-mean)*inv*lnw[c2+1] + lnb[c2+1];
  float dot = n0*gW[c0] + n1*gW[c0+1] + n2*gW[c2] + n3*gW[c2+1];
  #pragma unroll
  for (int mm = 1; mm < 64; mm <<= 1) dot += __shfl_xor(dot, mm, 64);
  const float gate = sigm(dot + gb[0]);
  float2 o;
  o.x = gate*lv.x + (1.f-gate)*mv.x;
  o.y = gate*lv.y + (1.f-gate)*mv.y;
  *(float2*)(out + (size_t)pair*128 + lane*2) = o;
}

extern "C" void kernel_launch(void* const* d_in, const int* in_sizes, int n_in,
                              void* d_out, int out_size, void* d_ws, size_t ws_size,
                              hipStream_t stream)
{
  const float* x       = (const float*)d_in[0];
  const float* Wih0    = (const float*)d_in[1];
  const float* WihR    = (const float*)d_in[2];
  const float* Whh     = (const float*)d_in[3];
  const float* bih     = (const float*)d_in[4];
  const float* bhh     = (const float*)d_in[5];
  const float* mprojW  = (const float*)d_in[6];
  const float* mprojB  = (const float*)d_in[7];
  const float* inprojW = (const float*)d_in[8];
  const float* convw   = (const float*)d_in[9];
  const float* convb   = (const float*)d_in[10];
  const float* xprojW  = (const float*)d_in[11];
  const float* dtW     = (const float*)d_in[12];
  const float* dtB     = (const float*)d_in[13];
  const float* Alog    = (const float*)d_in[14];
  const float* Dskip   = (const float*)d_in[15];
  const float* outprojW= (const float*)d_in[16];
  const float* lnw     = (const float*)d_in[17];
  const float* lnb     = (const float*)d_in[18];
  const float* gWt     = (const float*)d_in[19];
  const float* gb      = (const float*)d_in[20];

  float* WS = (float*)d_ws;
  const size_t M1 = 1048576;
  float* mamba_out = WS;                    // [NM,128]
  float* P     = WS + M1;
  float* G     = P;                         // [2][SEQ][4][256] = 4M1 (lstm)
  float* lstmA = P + 4*M1;                  // [NM,128]
  float* lstmB = P + 5*M1;                  // [NM,128]
  float* xi    = P + 6*M1;                  // [NM,256] (F0 out, F1 in)
  float* dtb   = P + 6*M1;                  // alias: [NM,256] (F2 out, F3 in)
  float* xc    = P + 8*M1;                  // [NM,256] (F1 out; F2, tail in)
  float* dbc   = P + 10*M1;                 // [NM,136] (F2 out, F3 in)
  float* wc    = P + 10*M1 + (size_t)NM*136;// [512][23]
  float* bvec  = wc + 512*23;               // [512]
  float* ysb   = P + 11*M1 + M1/4;          // [NM,256] (F3 out, tail in)
  const bool zOK = ws_size >= 65ull*1048576;
  float* zbuf  = zOK ? (P + 13*M1 + M1/4)   // [NM,256], written in l=0 launch
                     : (P + 6*M1);          // fallback: alias, tail z-gemm
  float* outp  = (float*)d_out;

  dim3 blk(256);

  // pre: fold mproj into in_proj
  wcomb_k<<<48, blk, 0, stream>>>(inprojW, mprojW, mprojB, wc, bvec);

  // ---- LSTM layers with mamba stages riding the scan launches ----
  const float* lin = x;
  float* louts[4] = {lstmA, lstmB, lstmA, lstmB};
  for (int l = 0; l < 4; ++l) {
    const float* w0; const float* w1; int K;
    if (l == 0) { w0 = Wih0; w1 = Wih0 + 256*23; K = 23; }
    else {
      w0 = WihR + (size_t)((l-1)*2 + 0)*256*128;
      w1 = WihR + (size_t)((l-1)*2 + 1)*256*128;
      K = 128;
    }
    gemm_k<<<dim3(8,128), blk, 0, stream>>>(lin, K, w0, w1, 256,
        bih + (l*2+0)*256, bhh + (l*2+0)*256,
        bih + (l*2+1)*256, bhh + (l*2+1)*256,
        G, NM, 512, K, 2);
    const float* Wl = Whh + (size_t)l*2*256*64;
    if (l == 0) {        // rider: xi = x @ W'[0:256]^T + b' (+ optional z)
      fused_k<<<2 + (zOK ? 1024 : 512), blk, 0, stream>>>(0, G, Wl, louts[l],
          x, 23, wc, bvec, xi, 256, 256, 23,
          zOK ? (wc + 256*23) : nullptr, zOK ? (bvec + 256) : nullptr,
          zOK ? zbuf : nullptr, nullptr, nullptr, nullptr, nullptr, nullptr);
    } else if (l == 1) { // rider: conv+silu (NM*256 / 256 blocks)
      fused_k<<<2 + 8192, blk, 0, stream>>>(1, G, Wl, louts[l],
          xi, 0, convw, convb, xc, 0, 0, 0,
          nullptr, nullptr, nullptr, nullptr, nullptr, nullptr, nullptr, nullptr);
    } else if (l == 2) { // rider: xproj (3 x 128 tiles) + fused dt
      fused_k<<<2 + 384, blk, 0, stream>>>(2, G, Wl, louts[l],
          xc, 256, xprojW, nullptr, dbc, 136, 136, 256,
          dtW, dtB, dtb, nullptr, nullptr, nullptr, nullptr, nullptr);
    } else {             // rider: mamba selective scan (256 blocks x 4 waves)
      fused_k<<<2 + 256, blk, 0, stream>>>(3, G, Wl, louts[l],
          nullptr, 0, nullptr, nullptr, nullptr, 0, 0, 0,
          nullptr, nullptr, nullptr, dbc, dtb, xc, Alog, ysb);
    }
    lin = louts[l];
  }

  // ---- tail: [z-gemm if not ridden], fused ycomb+out_proj, gate+mix ----
  if (!zOK) {
    gemm_k<<<dim3(4,128), blk, 0, stream>>>(x, 23, wc + 256*23, nullptr, 256,
        bvec + 256, nullptr, nullptr, nullptr, zbuf, NM, 256, 23, 0);
  }
  moutproj_k<<<dim3(2,128), blk, 0, stream>>>(zbuf, ysb, xc, Dskip,
      outprojW, mamba_out);
  combine_k<<<2048, blk, 0, stream>>>(lstmB, mamba_out, lnw, lnb, gWt, gb, outp);
}